// Round 15
// baseline (83.716 us; speedup 1.0000x reference)
//
#include <hip/hip_runtime.h>
#include <hip/hip_bf16.h>

#define BN 16
#define TN 2048
#define DN 64
#define EN 512
#define PAD 68   // bf16 row stride 136B
#define SQK 0.42466084f   // sqrt(0.125*log2(e)); Qb pre-scale so exp2(acc)=e^(s/8)

using f32x4  = __attribute__((ext_vector_type(4))) float;
using bf16x8 = __attribute__((ext_vector_type(8))) short;
using bf16x4 = __attribute__((ext_vector_type(4))) short;

static __device__ __forceinline__ short f2bf(float f) {
    __hip_bfloat16 h = __float2bfloat16(f);
    return __builtin_bit_cast(short, h);
}
static __device__ __forceinline__ float bf2f(short s) {
    return __bfloat162float(__builtin_bit_cast(__hip_bfloat16, s));
}
// barrier that makes LDS writes visible but does NOT drain vmcnt:
// in-flight global prefetch loads survive the barrier (T4 pattern).
static __device__ __forceinline__ void bar_lds() {
    asm volatile("s_waitcnt lgkmcnt(0)" ::: "memory");
    __builtin_amdgcn_s_barrier();
}

// ---------------------------------------------------------------------------
// Kernel W: split W^T into bf16 hi + lo. Unchanged.
// ---------------------------------------------------------------------------
__global__ __launch_bounds__(256) void wprep_kernel(
    const float* __restrict__ Wq, short* __restrict__ WTh,
    short* __restrict__ WTl)
{
    __shared__ float wlds[64][65];
    const int tid = threadIdx.x;
    const int k0 = blockIdx.x * 64;
    #pragma unroll
    for (int it = 0; it < 16; ++it) {
        int idx = it * 256 + tid;
        int k = idx >> 6, n = idx & 63;
        wlds[k][n] = Wq[(size_t)(k0 + k) * 64 + n];
    }
    __syncthreads();
    #pragma unroll
    for (int it = 0; it < 16; ++it) {
        int idx = it * 256 + tid;
        int n = idx >> 6, k = idx & 63;
        float v = wlds[k][n];
        short h = f2bf(v);
        short l = f2bf(v - bf2f(h));
        WTh[(size_t)n * EN + k0 + k] = h;
        WTl[(size_t)n * EN + k0 + k] = l;
    }
}

// ---------------------------------------------------------------------------
// Kernel A: Q = x @ W + bq via MFMA (bf16 hi+lo W, f32 accum). R11 structure;
// R15 change: Qb written PRE-SCALED by SQK (S-operand), QTb unscaled (V).
// ---------------------------------------------------------------------------
__global__ __launch_bounds__(256, 2) void qproj_kernel(
    const float* __restrict__ x, const short* __restrict__ WTh,
    const short* __restrict__ WTl, const float* __restrict__ bq,
    short* __restrict__ Qb, short* __restrict__ QTb)
{
    __shared__ short xh[2 * 64 * 40];
    __shared__ short wth[2 * 64 * 40];
    __shared__ short wtl[2 * 64 * 40];
    __shared__ short tl[64][68];

    const int tid = threadIdx.x;
    const int lane = tid & 63;
    const int wv = tid >> 6;
    const int c = lane & 15;
    const int g = lane >> 4;
    const int rowbase = blockIdx.x * 64;
    const int b = rowbase >> 11;
    const int tbase = rowbase & (TN - 1);

    const int sr = tid >> 3;
    const int sc4 = tid & 7;
    const size_t xr0 = (size_t)(rowbase + sr) * EN + sc4 * 4;
    const size_t xr1 = (size_t)(rowbase + 32 + sr) * EN + sc4 * 4;
    const size_t wr0 = (size_t)sr * EN + sc4 * 4;
    const size_t wr1 = (size_t)(32 + sr) * EN + sc4 * 4;

    float4 xa, xb;
    bf16x4 wa, wb, la, lb;

    xa = *reinterpret_cast<const float4*>(&x[xr0]);
    xb = *reinterpret_cast<const float4*>(&x[xr1]);
    wa = *reinterpret_cast<const bf16x4*>(&WTh[wr0]);
    wb = *reinterpret_cast<const bf16x4*>(&WTh[wr1]);
    la = *reinterpret_cast<const bf16x4*>(&WTl[wr0]);
    lb = *reinterpret_cast<const bf16x4*>(&WTl[wr1]);
    {
        bf16x4 h0, h1;
        #pragma unroll
        for (int j = 0; j < 4; ++j) { h0[j] = f2bf(xa[j]); h1[j] = f2bf(xb[j]); }
        *reinterpret_cast<bf16x4*>(&xh[sr * 40 + sc4 * 4]) = h0;
        *reinterpret_cast<bf16x4*>(&xh[(32 + sr) * 40 + sc4 * 4]) = h1;
        *reinterpret_cast<bf16x4*>(&wth[sr * 40 + sc4 * 4]) = wa;
        *reinterpret_cast<bf16x4*>(&wth[(32 + sr) * 40 + sc4 * 4]) = wb;
        *reinterpret_cast<bf16x4*>(&wtl[sr * 40 + sc4 * 4]) = la;
        *reinterpret_cast<bf16x4*>(&wtl[(32 + sr) * 40 + sc4 * 4]) = lb;
    }
    xa = *reinterpret_cast<const float4*>(&x[xr0 + 32]);
    xb = *reinterpret_cast<const float4*>(&x[xr1 + 32]);
    wa = *reinterpret_cast<const bf16x4*>(&WTh[wr0 + 32]);
    wb = *reinterpret_cast<const bf16x4*>(&WTh[wr1 + 32]);
    la = *reinterpret_cast<const bf16x4*>(&WTl[wr0 + 32]);
    lb = *reinterpret_cast<const bf16x4*>(&WTl[wr1 + 32]);
    bar_lds();

    f32x4 acc[4];
    #pragma unroll
    for (int nt = 0; nt < 4; ++nt) acc[nt] = (f32x4){0.f, 0.f, 0.f, 0.f};

    for (int t = 0; t < 16; ++t) {
        const int cur = t & 1;
        const int co = cur * 2560;
        if (t + 1 < 16) {
            const int wo = (cur ^ 1) * 2560;
            bf16x4 h0, h1;
            #pragma unroll
            for (int j = 0; j < 4; ++j) { h0[j] = f2bf(xa[j]); h1[j] = f2bf(xb[j]); }
            *reinterpret_cast<bf16x4*>(&xh[wo + sr * 40 + sc4 * 4]) = h0;
            *reinterpret_cast<bf16x4*>(&xh[wo + (32 + sr) * 40 + sc4 * 4]) = h1;
            *reinterpret_cast<bf16x4*>(&wth[wo + sr * 40 + sc4 * 4]) = wa;
            *reinterpret_cast<bf16x4*>(&wth[wo + (32 + sr) * 40 + sc4 * 4]) = wb;
            *reinterpret_cast<bf16x4*>(&wtl[wo + sr * 40 + sc4 * 4]) = la;
            *reinterpret_cast<bf16x4*>(&wtl[wo + (32 + sr) * 40 + sc4 * 4]) = lb;
        }
        if (t + 2 < 16) {
            const int kn = (t + 2) * 32;
            xa = *reinterpret_cast<const float4*>(&x[xr0 + kn]);
            xb = *reinterpret_cast<const float4*>(&x[xr1 + kn]);
            wa = *reinterpret_cast<const bf16x4*>(&WTh[wr0 + kn]);
            wb = *reinterpret_cast<const bf16x4*>(&WTh[wr1 + kn]);
            la = *reinterpret_cast<const bf16x4*>(&WTl[wr0 + kn]);
            lb = *reinterpret_cast<const bf16x4*>(&WTl[wr1 + kn]);
        }

        bf16x8 av = *reinterpret_cast<const bf16x8*>(&xh[co + (wv * 16 + c) * 40 + g * 8]);
        #pragma unroll
        for (int nt = 0; nt < 4; ++nt) {
            bf16x8 bh = *reinterpret_cast<const bf16x8*>(&wth[co + (nt * 16 + c) * 40 + g * 8]);
            bf16x8 bl = *reinterpret_cast<const bf16x8*>(&wtl[co + (nt * 16 + c) * 40 + g * 8]);
            acc[nt] = __builtin_amdgcn_mfma_f32_16x16x32_bf16(av, bh, acc[nt], 0, 0, 0);
            acc[nt] = __builtin_amdgcn_mfma_f32_16x16x32_bf16(av, bl, acc[nt], 0, 0, 0);
        }
        bar_lds();
    }

    __syncthreads();
    #pragma unroll
    for (int nt = 0; nt < 4; ++nt) {
        const float bias = bq[nt * 16 + c];
        #pragma unroll
        for (int r = 0; r < 4; ++r) {
            const int row = wv * 16 + g * 4 + r;
            const float q = acc[nt][r] + bias;
            Qb[(size_t)(rowbase + row) * DN + nt * 16 + c] = f2bf(q * SQK);
            tl[nt * 16 + c][row] = f2bf(q);
        }
    }
    __syncthreads();
    #pragma unroll
    for (int it = 0; it < 4; ++it) {
        int idx = it * 256 + tid;
        int d = idx >> 4;
        int j4 = (idx & 15) * 4;
        *reinterpret_cast<short4*>(&QTb[((size_t)(b * 64 + d)) * TN + tbase + j4]) =
            *reinterpret_cast<const short4*>(&tl[d][j4]);
    }
}

// ---------------------------------------------------------------------------
// Kernel B: partial column-softmax sums, z-split 4, R11 dbuf structure.
// R15 change: l = sum exp2(acc) (Qb pre-scaled; one mul per element removed).
// ---------------------------------------------------------------------------
__global__ __launch_bounds__(256, 4) void stats_kernel(
    const short* __restrict__ Qb, float* __restrict__ l_part)
{
    __shared__ short Qt[2 * 64 * PAD];
    const int tid = threadIdx.x;
    const int lane = tid & 63;
    const int wv = tid >> 6;
    const int c = lane & 15;
    const int g = lane >> 4;
    const int b = blockIdx.y;
    const int z = blockIdx.z;
    const int jbase = blockIdx.x * 64 + wv * 16;
    const short* Qbb = Qb + (size_t)b * TN * DN;

    bf16x8 a0 = *reinterpret_cast<const bf16x8*>(Qbb + (size_t)(jbase + c) * DN + g * 8);
    bf16x8 a1 = *reinterpret_cast<const bf16x8*>(Qbb + (size_t)(jbase + c) * DN + g * 8 + 32);

    const int srow = tid >> 2;
    const int schk = tid & 3;
    const int ilo = z * (TN / 4);
    const int NT = (TN / 4) / 64;            // 8 tiles

    bf16x8 v0, v1;
    v0 = *reinterpret_cast<const bf16x8*>(Qbb + (size_t)(ilo + srow) * DN + schk * 16);
    v1 = *reinterpret_cast<const bf16x8*>(Qbb + (size_t)(ilo + srow) * DN + schk * 16 + 8);
    *reinterpret_cast<bf16x8*>(&Qt[srow * PAD + schk * 16]) = v0;
    *reinterpret_cast<bf16x8*>(&Qt[srow * PAD + schk * 16 + 8]) = v1;
    v0 = *reinterpret_cast<const bf16x8*>(Qbb + (size_t)(ilo + 64 + srow) * DN + schk * 16);
    v1 = *reinterpret_cast<const bf16x8*>(Qbb + (size_t)(ilo + 64 + srow) * DN + schk * 16 + 8);
    bar_lds();

    float l[4] = {0.f, 0.f, 0.f, 0.f};
    for (int t = 0; t < NT; ++t) {
        const int cur = t & 1;
        const int co = cur * 64 * PAD;
        if (t + 1 < NT) {
            const int wo = (cur ^ 1) * 64 * PAD;
            *reinterpret_cast<bf16x8*>(&Qt[wo + srow * PAD + schk * 16]) = v0;
            *reinterpret_cast<bf16x8*>(&Qt[wo + srow * PAD + schk * 16 + 8]) = v1;
        }
        if (t + 2 < NT) {
            const int in_ = ilo + (t + 2) * 64;
            v0 = *reinterpret_cast<const bf16x8*>(Qbb + (size_t)(in_ + srow) * DN + schk * 16);
            v1 = *reinterpret_cast<const bf16x8*>(Qbb + (size_t)(in_ + srow) * DN + schk * 16 + 8);
        }
        #pragma unroll
        for (int it = 0; it < 4; ++it) {
            bf16x8 b0 = *reinterpret_cast<const bf16x8*>(&Qt[co + (it * 16 + c) * PAD + g * 8]);
            bf16x8 b1 = *reinterpret_cast<const bf16x8*>(&Qt[co + (it * 16 + c) * PAD + g * 8 + 32]);
            f32x4 acc = {0.f, 0.f, 0.f, 0.f};
            acc = __builtin_amdgcn_mfma_f32_16x16x32_bf16(a0, b0, acc, 0, 0, 0);
            acc = __builtin_amdgcn_mfma_f32_16x16x32_bf16(a1, b1, acc, 0, 0, 0);
            #pragma unroll
            for (int r = 0; r < 4; ++r)
                l[r] += __builtin_exp2f(acc[r]);
        }
        bar_lds();
    }
    #pragma unroll
    for (int r = 0; r < 4; ++r) {
        float v = l[r];
        v += __shfl_xor(v, 1);
        v += __shfl_xor(v, 2);
        v += __shfl_xor(v, 4);
        v += __shfl_xor(v, 8);
        l[r] = v;
    }
    if (c == 0) {
        #pragma unroll
        for (int r = 0; r < 4; ++r)
            l_part[((size_t)z * BN + b) * TN + jbase + g * 4 + r] = l[r];
    }
}

// ---------------------------------------------------------------------------
// Kernel F: RT[b][d][j] = QT[b][d][j] / sum_z l_part[z][b][j]. Unchanged.
// ---------------------------------------------------------------------------
__global__ __launch_bounds__(256) void fuse_kernel(
    const short* __restrict__ QTb, const float* __restrict__ l_part,
    short* __restrict__ RT)
{
    const int idx = blockIdx.x * 256 + threadIdx.x;
    const int c8 = idx & 255;
    const int bd = idx >> 8;
    const int b = bd >> 6;
    const int j0 = c8 * 8;

    bf16x8 q = *reinterpret_cast<const bf16x8*>(&QTb[(size_t)bd * TN + j0]);
    const float* lp0 = l_part + (size_t)b * TN + j0;
    const float* lp1 = l_part + (size_t)(BN + b) * TN + j0;
    const float* lp2 = l_part + (size_t)(2 * BN + b) * TN + j0;
    const float* lp3 = l_part + (size_t)(3 * BN + b) * TN + j0;
    bf16x8 r;
    #pragma unroll
    for (int t = 0; t < 8; ++t)
        r[t] = f2bf(bf2f(q[t]) / (lp0[t] + lp1[t] + lp2[t] + lp3[t]));
    *reinterpret_cast<bf16x8*>(&RT[(size_t)bd * TN + j0]) = r;
}

// ---------------------------------------------------------------------------
// Kernel C (v13): out_partial[i,:] = sum_{j in z-half} exp2(acc) * RT[:,j]
// R11 structure with TWO R15 changes:
//  (1) staging ds_writes moved AFTER phase B (prefetch t+2 after them): the
//      phase A->B lgkmcnt(0) fence now covers only phase-A's own LDS ops;
//      staging latency drains under the end-of-iter barrier instead.
//  (2) P = exp2(acc) (Qb pre-scaled) — one VALU mul per S-element removed.
// ---------------------------------------------------------------------------
__global__ __launch_bounds__(256, 2) void pv_kernel(
    const short* __restrict__ Qb, const short* __restrict__ RT,
    float* __restrict__ out0, float* __restrict__ out1)
{
    __shared__ short Qt[2 * 64 * PAD];    // Q[j-local][d] (scaled)
    __shared__ short RTt[2 * 64 * PAD];   // RT[d][j-local]
    __shared__ short Pt[8][16 * PAD];     // per (wave,ih): P tile

    const int tid = threadIdx.x;
    const int lane = tid & 63;
    const int wv = tid >> 6;
    const int c = lane & 15;
    const int g = lane >> 4;
    const int b = blockIdx.y;
    const int z = blockIdx.z;
    const int ibase = blockIdx.x * 128 + wv * 32;
    const short* Qbb = Qb + (size_t)b * TN * DN;
    const short* RTb = RT + (size_t)b * DN * TN;

    bf16x8 bi[2][2];
    #pragma unroll
    for (int ih = 0; ih < 2; ++ih) {
        const short* p = Qbb + (size_t)(ibase + ih * 16 + c) * DN + g * 8;
        bi[ih][0] = *reinterpret_cast<const bf16x8*>(p);
        bi[ih][1] = *reinterpret_cast<const bf16x8*>(p + 32);
    }

    f32x4 o[4][2];
    #pragma unroll
    for (int dt = 0; dt < 4; ++dt)
        #pragma unroll
        for (int ih = 0; ih < 2; ++ih)
            o[dt][ih] = (f32x4){0.f, 0.f, 0.f, 0.f};

    const int srow = tid >> 2;
    const int schk = tid & 3;
    const int jlo = z * (TN / 2);
    const int NT = (TN / 2) / 64;            // 16 tiles

    bf16x8 vq0, vq1, vt0, vt1;
    vq0 = *reinterpret_cast<const bf16x8*>(Qbb + (size_t)(jlo + srow) * DN + schk * 16);
    vq1 = *reinterpret_cast<const bf16x8*>(Qbb + (size_t)(jlo + srow) * DN + schk * 16 + 8);
    vt0 = *reinterpret_cast<const bf16x8*>(RTb + (size_t)srow * TN + jlo + schk * 16);
    vt1 = *reinterpret_cast<const bf16x8*>(RTb + (size_t)srow * TN + jlo + schk * 16 + 8);
    *reinterpret_cast<bf16x8*>(&Qt[srow * PAD + schk * 16]) = vq0;
    *reinterpret_cast<bf16x8*>(&Qt[srow * PAD + schk * 16 + 8]) = vq1;
    *reinterpret_cast<bf16x8*>(&RTt[srow * PAD + schk * 16]) = vt0;
    *reinterpret_cast<bf16x8*>(&RTt[srow * PAD + schk * 16 + 8]) = vt1;
    vq0 = *reinterpret_cast<const bf16x8*>(Qbb + (size_t)(jlo + 64 + srow) * DN + schk * 16);
    vq1 = *reinterpret_cast<const bf16x8*>(Qbb + (size_t)(jlo + 64 + srow) * DN + schk * 16 + 8);
    vt0 = *reinterpret_cast<const bf16x8*>(RTb + (size_t)srow * TN + jlo + 64 + schk * 16);
    vt1 = *reinterpret_cast<const bf16x8*>(RTb + (size_t)srow * TN + jlo + 64 + schk * 16 + 8);
    bar_lds();

    for (int t = 0; t < NT; ++t) {
        const int cur = t & 1;
        const int co = cur * 64 * PAD;

        // preload phase-B A-frags (RT rows) from the current buffer
        bf16x8 aq[4][2];
        #pragma unroll
        for (int dt = 0; dt < 4; ++dt) {
            aq[dt][0] = *reinterpret_cast<const bf16x8*>(&RTt[co + (dt * 16 + c) * PAD + g * 8]);
            aq[dt][1] = *reinterpret_cast<const bf16x8*>(&RTt[co + (dt * 16 + c) * PAD + 32 + g * 8]);
        }

        // --- phase A: MFMA1 S^T tiles -> P = exp2(acc) -> Pt (wave-private) ---
        #pragma unroll
        for (int jt = 0; jt < 4; ++jt) {
            bf16x8 a0 = *reinterpret_cast<const bf16x8*>(&Qt[co + (jt * 16 + c) * PAD + g * 8]);
            bf16x8 a1 = *reinterpret_cast<const bf16x8*>(&Qt[co + (jt * 16 + c) * PAD + g * 8 + 32]);
            #pragma unroll
            for (int ih = 0; ih < 2; ++ih) {
                f32x4 accs = {0.f, 0.f, 0.f, 0.f};
                accs = __builtin_amdgcn_mfma_f32_16x16x32_bf16(a0, bi[ih][0], accs, 0, 0, 0);
                accs = __builtin_amdgcn_mfma_f32_16x16x32_bf16(a1, bi[ih][1], accs, 0, 0, 0);
                bf16x4 pw;
                #pragma unroll
                for (int r = 0; r < 4; ++r)
                    pw[r] = f2bf(__builtin_exp2f(accs[r]));
                *reinterpret_cast<bf16x4*>(&Pt[wv * 2 + ih][c * PAD + jt * 16 + g * 4]) = pw;
            }
        }
        // thin fence: only phase-A LDS ops are outstanding here now
        asm volatile("s_waitcnt lgkmcnt(0)" ::: "memory");
        __builtin_amdgcn_sched_barrier(0);

        // --- phase B: MFMA2 outT[d][i] += RT[d][j] * P[j][i], both i-halves ---
        #pragma unroll
        for (int ih = 0; ih < 2; ++ih) {
            bf16x8 p0 = *reinterpret_cast<const bf16x8*>(&Pt[wv * 2 + ih][c * PAD + g * 8]);
            bf16x8 p1 = *reinterpret_cast<const bf16x8*>(&Pt[wv * 2 + ih][c * PAD + 32 + g * 8]);
            #pragma unroll
            for (int dt = 0; dt < 4; ++dt) {
                o[dt][ih] = __builtin_amdgcn_mfma_f32_16x16x32_bf16(aq[dt][0], p0, o[dt][ih], 0, 0, 0);
                o[dt][ih] = __builtin_amdgcn_mfma_f32_16x16x32_bf16(aq[dt][1], p1, o[dt][ih], 0, 0, 0);
            }
        }

        // staging writes for t+1 (moved post-phase-B), then prefetch t+2
        if (t + 1 < NT) {
            const int wo = (cur ^ 1) * 64 * PAD;
            *reinterpret_cast<bf16x8*>(&Qt[wo + srow * PAD + schk * 16]) = vq0;
            *reinterpret_cast<bf16x8*>(&Qt[wo + srow * PAD + schk * 16 + 8]) = vq1;
            *reinterpret_cast<bf16x8*>(&RTt[wo + srow * PAD + schk * 16]) = vt0;
            *reinterpret_cast<bf16x8*>(&RTt[wo + srow * PAD + schk * 16 + 8]) = vt1;
        }
        if (t + 2 < NT) {
            const int jn = jlo + (t + 2) * 64;
            vq0 = *reinterpret_cast<const bf16x8*>(Qbb + (size_t)(jn + srow) * DN + schk * 16);
            vq1 = *reinterpret_cast<const bf16x8*>(Qbb + (size_t)(jn + srow) * DN + schk * 16 + 8);
            vt0 = *reinterpret_cast<const bf16x8*>(RTb + (size_t)srow * TN + jn + schk * 16);
            vt1 = *reinterpret_cast<const bf16x8*>(RTb + (size_t)srow * TN + jn + schk * 16 + 8);
        }
        bar_lds();
    }

    // epilogue: lane holds outT[dt*16+g*4+r][ibase+ih*16+c] -> f32x4 stores
    float* outb = (z ? out1 : out0) + (size_t)b * TN * DN;
    #pragma unroll
    for (int dt = 0; dt < 4; ++dt) {
        #pragma unroll
        for (int ih = 0; ih < 2; ++ih) {
            float4 v4;
            v4.x = o[dt][ih][0]; v4.y = o[dt][ih][1];
            v4.z = o[dt][ih][2]; v4.w = o[dt][ih][3];
            *reinterpret_cast<float4*>(
                &outb[(size_t)(ibase + ih * 16 + c) * DN + dt * 16 + g * 4]) = v4;
        }
    }
}

// ---------------------------------------------------------------------------
// Kernel R: out += part1 (exactly 1 float4 per thread).
// ---------------------------------------------------------------------------
__global__ __launch_bounds__(256) void reduce_kernel(
    float* __restrict__ out, const float* __restrict__ part1)
{
    const size_t i = (size_t)blockIdx.x * 256 + threadIdx.x;
    float4 a = reinterpret_cast<float4*>(out)[i];
    float4 b = reinterpret_cast<const float4*>(part1)[i];
    a.x += b.x; a.y += b.y; a.z += b.z; a.w += b.w;
    reinterpret_cast<float4*>(out)[i] = a;
}

extern "C" void kernel_launch(void* const* d_in, const int* in_sizes, int n_in,
                              void* d_out, int out_size, void* d_ws, size_t ws_size,
                              hipStream_t stream) {
    const float* x  = (const float*)d_in[0];
    const float* Wq = (const float*)d_in[1];
    const float* bq = (const float*)d_in[2];
    float* out = (float*)d_out;

    short* Qb   = (short*)d_ws;                           // 4 MB (scaled by SQK)
    short* QTb  = Qb + (size_t)BN * TN * DN;              // 4 MB (unscaled)
    short* RT   = QTb + (size_t)BN * TN * DN;             // 4 MB
    float* lpar = (float*)(RT + (size_t)BN * TN * DN);    // 512 KB
    short* WTh  = (short*)(lpar + (size_t)4 * BN * TN);   // 64 KB
    short* WTl  = WTh + (size_t)DN * EN;                  // 64 KB
    float* part1 = (float*)(WTl + (size_t)DN * EN);       // 8 MB

    wprep_kernel<<<dim3(EN / 64), dim3(256), 0, stream>>>(Wq, WTh, WTl);
    qproj_kernel<<<dim3(BN * TN / 64), dim3(256), 0, stream>>>(x, WTh, WTl, bq, Qb, QTb);
    stats_kernel<<<dim3(TN / 64, BN, 4), dim3(256), 0, stream>>>(Qb, lpar);
    fuse_kernel<<<dim3(BN * DN * TN / 8 / 256), dim3(256), 0, stream>>>(QTb, lpar, RT);
    pv_kernel<<<dim3(TN / 128, BN, 2), dim3(256), 0, stream>>>(Qb, RT, out, part1);
    reduce_kernel<<<dim3(BN * TN * DN / 4 / 256), dim3(256), 0, stream>>>(out, part1);
}

// Round 16
// 78.564 us; speedup vs baseline: 1.0656x; 1.0656x over previous
//
#include <hip/hip_runtime.h>
#include <hip/hip_bf16.h>

#define BN 16
#define TN 2048
#define DN 64
#define EN 512
#define PAD 68   // bf16 row stride 136B

using f32x4  = __attribute__((ext_vector_type(4))) float;
using bf16x8 = __attribute__((ext_vector_type(8))) short;
using bf16x4 = __attribute__((ext_vector_type(4))) short;

static __device__ __forceinline__ short f2bf(float f) {
    __hip_bfloat16 h = __float2bfloat16(f);
    return __builtin_bit_cast(short, h);
}
static __device__ __forceinline__ float bf2f(short s) {
    return __bfloat162float(__builtin_bit_cast(__hip_bfloat16, s));
}
// barrier that makes LDS writes visible but does NOT drain vmcnt:
// in-flight global prefetch loads survive the barrier (T4 pattern).
static __device__ __forceinline__ void bar_lds() {
    asm volatile("s_waitcnt lgkmcnt(0)" ::: "memory");
    __builtin_amdgcn_s_barrier();
}

// ---------------------------------------------------------------------------
// Kernel W: split W^T into bf16 hi + lo.
// ---------------------------------------------------------------------------
__global__ __launch_bounds__(256) void wprep_kernel(
    const float* __restrict__ Wq, short* __restrict__ WTh,
    short* __restrict__ WTl)
{
    __shared__ float wlds[64][65];
    const int tid = threadIdx.x;
    const int k0 = blockIdx.x * 64;
    #pragma unroll
    for (int it = 0; it < 16; ++it) {
        int idx = it * 256 + tid;
        int k = idx >> 6, n = idx & 63;
        wlds[k][n] = Wq[(size_t)(k0 + k) * 64 + n];
    }
    __syncthreads();
    #pragma unroll
    for (int it = 0; it < 16; ++it) {
        int idx = it * 256 + tid;
        int n = idx >> 6, k = idx & 63;
        float v = wlds[k][n];
        short h = f2bf(v);
        short l = f2bf(v - bf2f(h));
        WTh[(size_t)n * EN + k0 + k] = h;
        WTl[(size_t)n * EN + k0 + k] = l;
    }
}

// ---------------------------------------------------------------------------
// Kernel A (v3): Q = x @ W + bq via MFMA (bf16 hi+lo W, f32 accum).
// Double-buffered LDS, ONE lgkm-only barrier per K-step. (R11 verbatim.)
// ---------------------------------------------------------------------------
__global__ __launch_bounds__(256, 2) void qproj_kernel(
    const float* __restrict__ x, const short* __restrict__ WTh,
    const short* __restrict__ WTl, const float* __restrict__ bq,
    short* __restrict__ Qb, short* __restrict__ QTb)
{
    __shared__ short xh[2 * 64 * 40];
    __shared__ short wth[2 * 64 * 40];
    __shared__ short wtl[2 * 64 * 40];
    __shared__ short tl[64][68];

    const int tid = threadIdx.x;
    const int lane = tid & 63;
    const int wv = tid >> 6;
    const int c = lane & 15;
    const int g = lane >> 4;
    const int rowbase = blockIdx.x * 64;
    const int b = rowbase >> 11;
    const int tbase = rowbase & (TN - 1);

    const int sr = tid >> 3;
    const int sc4 = tid & 7;
    const size_t xr0 = (size_t)(rowbase + sr) * EN + sc4 * 4;
    const size_t xr1 = (size_t)(rowbase + 32 + sr) * EN + sc4 * 4;
    const size_t wr0 = (size_t)sr * EN + sc4 * 4;
    const size_t wr1 = (size_t)(32 + sr) * EN + sc4 * 4;

    float4 xa, xb;
    bf16x4 wa, wb, la, lb;

    xa = *reinterpret_cast<const float4*>(&x[xr0]);
    xb = *reinterpret_cast<const float4*>(&x[xr1]);
    wa = *reinterpret_cast<const bf16x4*>(&WTh[wr0]);
    wb = *reinterpret_cast<const bf16x4*>(&WTh[wr1]);
    la = *reinterpret_cast<const bf16x4*>(&WTl[wr0]);
    lb = *reinterpret_cast<const bf16x4*>(&WTl[wr1]);
    {
        bf16x4 h0, h1;
        #pragma unroll
        for (int j = 0; j < 4; ++j) { h0[j] = f2bf(xa[j]); h1[j] = f2bf(xb[j]); }
        *reinterpret_cast<bf16x4*>(&xh[sr * 40 + sc4 * 4]) = h0;
        *reinterpret_cast<bf16x4*>(&xh[(32 + sr) * 40 + sc4 * 4]) = h1;
        *reinterpret_cast<bf16x4*>(&wth[sr * 40 + sc4 * 4]) = wa;
        *reinterpret_cast<bf16x4*>(&wth[(32 + sr) * 40 + sc4 * 4]) = wb;
        *reinterpret_cast<bf16x4*>(&wtl[sr * 40 + sc4 * 4]) = la;
        *reinterpret_cast<bf16x4*>(&wtl[(32 + sr) * 40 + sc4 * 4]) = lb;
    }
    xa = *reinterpret_cast<const float4*>(&x[xr0 + 32]);
    xb = *reinterpret_cast<const float4*>(&x[xr1 + 32]);
    wa = *reinterpret_cast<const bf16x4*>(&WTh[wr0 + 32]);
    wb = *reinterpret_cast<const bf16x4*>(&WTh[wr1 + 32]);
    la = *reinterpret_cast<const bf16x4*>(&WTl[wr0 + 32]);
    lb = *reinterpret_cast<const bf16x4*>(&WTl[wr1 + 32]);
    bar_lds();

    f32x4 acc[4];
    #pragma unroll
    for (int nt = 0; nt < 4; ++nt) acc[nt] = (f32x4){0.f, 0.f, 0.f, 0.f};

    for (int t = 0; t < 16; ++t) {
        const int cur = t & 1;
        const int co = cur * 2560;
        if (t + 1 < 16) {
            const int wo = (cur ^ 1) * 2560;
            bf16x4 h0, h1;
            #pragma unroll
            for (int j = 0; j < 4; ++j) { h0[j] = f2bf(xa[j]); h1[j] = f2bf(xb[j]); }
            *reinterpret_cast<bf16x4*>(&xh[wo + sr * 40 + sc4 * 4]) = h0;
            *reinterpret_cast<bf16x4*>(&xh[wo + (32 + sr) * 40 + sc4 * 4]) = h1;
            *reinterpret_cast<bf16x4*>(&wth[wo + sr * 40 + sc4 * 4]) = wa;
            *reinterpret_cast<bf16x4*>(&wth[wo + (32 + sr) * 40 + sc4 * 4]) = wb;
            *reinterpret_cast<bf16x4*>(&wtl[wo + sr * 40 + sc4 * 4]) = la;
            *reinterpret_cast<bf16x4*>(&wtl[wo + (32 + sr) * 40 + sc4 * 4]) = lb;
        }
        if (t + 2 < 16) {
            const int kn = (t + 2) * 32;
            xa = *reinterpret_cast<const float4*>(&x[xr0 + kn]);
            xb = *reinterpret_cast<const float4*>(&x[xr1 + kn]);
            wa = *reinterpret_cast<const bf16x4*>(&WTh[wr0 + kn]);
            wb = *reinterpret_cast<const bf16x4*>(&WTh[wr1 + kn]);
            la = *reinterpret_cast<const bf16x4*>(&WTl[wr0 + kn]);
            lb = *reinterpret_cast<const bf16x4*>(&WTl[wr1 + kn]);
        }

        bf16x8 av = *reinterpret_cast<const bf16x8*>(&xh[co + (wv * 16 + c) * 40 + g * 8]);
        #pragma unroll
        for (int nt = 0; nt < 4; ++nt) {
            bf16x8 bh = *reinterpret_cast<const bf16x8*>(&wth[co + (nt * 16 + c) * 40 + g * 8]);
            bf16x8 bl = *reinterpret_cast<const bf16x8*>(&wtl[co + (nt * 16 + c) * 40 + g * 8]);
            acc[nt] = __builtin_amdgcn_mfma_f32_16x16x32_bf16(av, bh, acc[nt], 0, 0, 0);
            acc[nt] = __builtin_amdgcn_mfma_f32_16x16x32_bf16(av, bl, acc[nt], 0, 0, 0);
        }
        bar_lds();
    }

    __syncthreads();
    #pragma unroll
    for (int nt = 0; nt < 4; ++nt) {
        const float bias = bq[nt * 16 + c];
        #pragma unroll
        for (int r = 0; r < 4; ++r) {
            const int row = wv * 16 + g * 4 + r;
            short qb = f2bf(acc[nt][r] + bias);
            Qb[(size_t)(rowbase + row) * DN + nt * 16 + c] = qb;
            tl[nt * 16 + c][row] = qb;
        }
    }
    __syncthreads();
    #pragma unroll
    for (int it = 0; it < 4; ++it) {
        int idx = it * 256 + tid;
        int d = idx >> 4;
        int j4 = (idx & 15) * 4;
        *reinterpret_cast<short4*>(&QTb[((size_t)(b * 64 + d)) * TN + tbase + j4]) =
            *reinterpret_cast<const short4*>(&tl[d][j4]);
    }
}

// ---------------------------------------------------------------------------
// Kernel B (v9): partial column-softmax sums, z-split 4. Double-buffered Qt,
// one lgkm-only barrier per i-tile. (R11 verbatim.)
// ---------------------------------------------------------------------------
__global__ __launch_bounds__(256, 4) void stats_kernel(
    const short* __restrict__ Qb, float* __restrict__ l_part)
{
    __shared__ short Qt[2 * 64 * PAD];
    const int tid = threadIdx.x;
    const int lane = tid & 63;
    const int wv = tid >> 6;
    const int c = lane & 15;
    const int g = lane >> 4;
    const int b = blockIdx.y;
    const int z = blockIdx.z;
    const int jbase = blockIdx.x * 64 + wv * 16;
    const short* Qbb = Qb + (size_t)b * TN * DN;

    bf16x8 a0 = *reinterpret_cast<const bf16x8*>(Qbb + (size_t)(jbase + c) * DN + g * 8);
    bf16x8 a1 = *reinterpret_cast<const bf16x8*>(Qbb + (size_t)(jbase + c) * DN + g * 8 + 32);

    const int srow = tid >> 2;
    const int schk = tid & 3;
    const int ilo = z * (TN / 4);
    const int NT = (TN / 4) / 64;            // 8 tiles

    bf16x8 v0, v1;
    v0 = *reinterpret_cast<const bf16x8*>(Qbb + (size_t)(ilo + srow) * DN + schk * 16);
    v1 = *reinterpret_cast<const bf16x8*>(Qbb + (size_t)(ilo + srow) * DN + schk * 16 + 8);
    *reinterpret_cast<bf16x8*>(&Qt[srow * PAD + schk * 16]) = v0;
    *reinterpret_cast<bf16x8*>(&Qt[srow * PAD + schk * 16 + 8]) = v1;
    v0 = *reinterpret_cast<const bf16x8*>(Qbb + (size_t)(ilo + 64 + srow) * DN + schk * 16);
    v1 = *reinterpret_cast<const bf16x8*>(Qbb + (size_t)(ilo + 64 + srow) * DN + schk * 16 + 8);
    bar_lds();

    float l[4] = {0.f, 0.f, 0.f, 0.f};
    for (int t = 0; t < NT; ++t) {
        const int cur = t & 1;
        const int co = cur * 64 * PAD;
        if (t + 1 < NT) {
            const int wo = (cur ^ 1) * 64 * PAD;
            *reinterpret_cast<bf16x8*>(&Qt[wo + srow * PAD + schk * 16]) = v0;
            *reinterpret_cast<bf16x8*>(&Qt[wo + srow * PAD + schk * 16 + 8]) = v1;
        }
        if (t + 2 < NT) {
            const int in_ = ilo + (t + 2) * 64;
            v0 = *reinterpret_cast<const bf16x8*>(Qbb + (size_t)(in_ + srow) * DN + schk * 16);
            v1 = *reinterpret_cast<const bf16x8*>(Qbb + (size_t)(in_ + srow) * DN + schk * 16 + 8);
        }
        #pragma unroll
        for (int it = 0; it < 4; ++it) {
            bf16x8 b0 = *reinterpret_cast<const bf16x8*>(&Qt[co + (it * 16 + c) * PAD + g * 8]);
            bf16x8 b1 = *reinterpret_cast<const bf16x8*>(&Qt[co + (it * 16 + c) * PAD + g * 8 + 32]);
            f32x4 acc = {0.f, 0.f, 0.f, 0.f};
            acc = __builtin_amdgcn_mfma_f32_16x16x32_bf16(a0, b0, acc, 0, 0, 0);
            acc = __builtin_amdgcn_mfma_f32_16x16x32_bf16(a1, b1, acc, 0, 0, 0);
            #pragma unroll
            for (int r = 0; r < 4; ++r)
                l[r] += __expf(acc[r] * 0.125f);
        }
        bar_lds();
    }
    #pragma unroll
    for (int r = 0; r < 4; ++r) {
        float v = l[r];
        v += __shfl_xor(v, 1);
        v += __shfl_xor(v, 2);
        v += __shfl_xor(v, 4);
        v += __shfl_xor(v, 8);
        l[r] = v;
    }
    if (c == 0) {
        #pragma unroll
        for (int r = 0; r < 4; ++r)
            l_part[((size_t)z * BN + b) * TN + jbase + g * 4 + r] = l[r];
    }
}

// ---------------------------------------------------------------------------
// Kernel F: RT[b][d][j] = QT[b][d][j] / sum_z l_part[z][b][j]. (R11 verbatim.)
// ---------------------------------------------------------------------------
__global__ __launch_bounds__(256) void fuse_kernel(
    const short* __restrict__ QTb, const float* __restrict__ l_part,
    short* __restrict__ RT)
{
    const int idx = blockIdx.x * 256 + threadIdx.x;
    const int c8 = idx & 255;
    const int bd = idx >> 8;
    const int b = bd >> 6;
    const int j0 = c8 * 8;

    bf16x8 q = *reinterpret_cast<const bf16x8*>(&QTb[(size_t)bd * TN + j0]);
    const float* lp0 = l_part + (size_t)b * TN + j0;
    const float* lp1 = l_part + (size_t)(BN + b) * TN + j0;
    const float* lp2 = l_part + (size_t)(2 * BN + b) * TN + j0;
    const float* lp3 = l_part + (size_t)(3 * BN + b) * TN + j0;
    bf16x8 r;
    #pragma unroll
    for (int t = 0; t < 8; ++t)
        r[t] = f2bf(bf2f(q[t]) / (lp0[t] + lp1[t] + lp2[t] + lp3[t]));
    *reinterpret_cast<bf16x8*>(&RT[(size_t)bd * TN + j0]) = r;
}

// ---------------------------------------------------------------------------
// Kernel C (v9): out_partial[i,:] = sum_{j in z-half} exp(S/8) * RT[:,j]
// 128-i blocks (4 waves x 32 i), grid (TN/128, BN, 2) = 512. Double-buffered
// Qt/RTt, ONE lgkm-only barrier per j-tile; tile t+2 loads in flight across
// it. Pt wave-private with lgkmcnt fence. (R11 verbatim — measured best.)
// ---------------------------------------------------------------------------
__global__ __launch_bounds__(256, 2) void pv_kernel(
    const short* __restrict__ Qb, const short* __restrict__ RT,
    float* __restrict__ out0, float* __restrict__ out1)
{
    __shared__ short Qt[2 * 64 * PAD];    // Q[j-local][d]
    __shared__ short RTt[2 * 64 * PAD];   // RT[d][j-local]
    __shared__ short Pt[8][16 * PAD];     // per (wave,ih): P tile

    const int tid = threadIdx.x;
    const int lane = tid & 63;
    const int wv = tid >> 6;
    const int c = lane & 15;
    const int g = lane >> 4;
    const int b = blockIdx.y;
    const int z = blockIdx.z;
    const int ibase = blockIdx.x * 128 + wv * 32;
    const short* Qbb = Qb + (size_t)b * TN * DN;
    const short* RTb = RT + (size_t)b * DN * TN;

    bf16x8 bi[2][2];
    #pragma unroll
    for (int ih = 0; ih < 2; ++ih) {
        const short* p = Qbb + (size_t)(ibase + ih * 16 + c) * DN + g * 8;
        bi[ih][0] = *reinterpret_cast<const bf16x8*>(p);
        bi[ih][1] = *reinterpret_cast<const bf16x8*>(p + 32);
    }

    f32x4 o[4][2];
    #pragma unroll
    for (int dt = 0; dt < 4; ++dt)
        #pragma unroll
        for (int ih = 0; ih < 2; ++ih)
            o[dt][ih] = (f32x4){0.f, 0.f, 0.f, 0.f};

    const int srow = tid >> 2;
    const int schk = tid & 3;
    const int jlo = z * (TN / 2);
    const int NT = (TN / 2) / 64;            // 16 tiles

    bf16x8 vq0, vq1, vt0, vt1;
    vq0 = *reinterpret_cast<const bf16x8*>(Qbb + (size_t)(jlo + srow) * DN + schk * 16);
    vq1 = *reinterpret_cast<const bf16x8*>(Qbb + (size_t)(jlo + srow) * DN + schk * 16 + 8);
    vt0 = *reinterpret_cast<const bf16x8*>(RTb + (size_t)srow * TN + jlo + schk * 16);
    vt1 = *reinterpret_cast<const bf16x8*>(RTb + (size_t)srow * TN + jlo + schk * 16 + 8);
    *reinterpret_cast<bf16x8*>(&Qt[srow * PAD + schk * 16]) = vq0;
    *reinterpret_cast<bf16x8*>(&Qt[srow * PAD + schk * 16 + 8]) = vq1;
    *reinterpret_cast<bf16x8*>(&RTt[srow * PAD + schk * 16]) = vt0;
    *reinterpret_cast<bf16x8*>(&RTt[srow * PAD + schk * 16 + 8]) = vt1;
    vq0 = *reinterpret_cast<const bf16x8*>(Qbb + (size_t)(jlo + 64 + srow) * DN + schk * 16);
    vq1 = *reinterpret_cast<const bf16x8*>(Qbb + (size_t)(jlo + 64 + srow) * DN + schk * 16 + 8);
    vt0 = *reinterpret_cast<const bf16x8*>(RTb + (size_t)srow * TN + jlo + 64 + schk * 16);
    vt1 = *reinterpret_cast<const bf16x8*>(RTb + (size_t)srow * TN + jlo + 64 + schk * 16 + 8);
    bar_lds();

    for (int t = 0; t < NT; ++t) {
        const int cur = t & 1;
        const int co = cur * 64 * PAD;
        if (t + 1 < NT) {
            const int wo = (cur ^ 1) * 64 * PAD;
            *reinterpret_cast<bf16x8*>(&Qt[wo + srow * PAD + schk * 16]) = vq0;
            *reinterpret_cast<bf16x8*>(&Qt[wo + srow * PAD + schk * 16 + 8]) = vq1;
            *reinterpret_cast<bf16x8*>(&RTt[wo + srow * PAD + schk * 16]) = vt0;
            *reinterpret_cast<bf16x8*>(&RTt[wo + srow * PAD + schk * 16 + 8]) = vt1;
        }
        if (t + 2 < NT) {
            const int jn = jlo + (t + 2) * 64;
            vq0 = *reinterpret_cast<const bf16x8*>(Qbb + (size_t)(jn + srow) * DN + schk * 16);
            vq1 = *reinterpret_cast<const bf16x8*>(Qbb + (size_t)(jn + srow) * DN + schk * 16 + 8);
            vt0 = *reinterpret_cast<const bf16x8*>(RTb + (size_t)srow * TN + jn + schk * 16);
            vt1 = *reinterpret_cast<const bf16x8*>(RTb + (size_t)srow * TN + jn + schk * 16 + 8);
        }

        // preload phase-B A-frags (RT rows)
        bf16x8 aq[4][2];
        #pragma unroll
        for (int dt = 0; dt < 4; ++dt) {
            aq[dt][0] = *reinterpret_cast<const bf16x8*>(&RTt[co + (dt * 16 + c) * PAD + g * 8]);
            aq[dt][1] = *reinterpret_cast<const bf16x8*>(&RTt[co + (dt * 16 + c) * PAD + 32 + g * 8]);
        }

        // --- phase A: MFMA1 S^T tiles -> P = exp(s/8) -> Pt (wave-private) ---
        #pragma unroll
        for (int jt = 0; jt < 4; ++jt) {
            bf16x8 a0 = *reinterpret_cast<const bf16x8*>(&Qt[co + (jt * 16 + c) * PAD + g * 8]);
            bf16x8 a1 = *reinterpret_cast<const bf16x8*>(&Qt[co + (jt * 16 + c) * PAD + g * 8 + 32]);
            #pragma unroll
            for (int ih = 0; ih < 2; ++ih) {
                f32x4 accs = {0.f, 0.f, 0.f, 0.f};
                accs = __builtin_amdgcn_mfma_f32_16x16x32_bf16(a0, bi[ih][0], accs, 0, 0, 0);
                accs = __builtin_amdgcn_mfma_f32_16x16x32_bf16(a1, bi[ih][1], accs, 0, 0, 0);
                bf16x4 pw;
                #pragma unroll
                for (int r = 0; r < 4; ++r)
                    pw[r] = f2bf(__expf(accs[r] * 0.125f));
                *reinterpret_cast<bf16x4*>(&Pt[wv * 2 + ih][c * PAD + jt * 16 + g * 4]) = pw;
            }
        }
        asm volatile("s_waitcnt lgkmcnt(0)" ::: "memory");
        __builtin_amdgcn_sched_barrier(0);

        // --- phase B: MFMA2 outT[d][i] += RT[d][j] * P[j][i], both i-halves ---
        #pragma unroll
        for (int ih = 0; ih < 2; ++ih) {
            bf16x8 p0 = *reinterpret_cast<const bf16x8*>(&Pt[wv * 2 + ih][c * PAD + g * 8]);
            bf16x8 p1 = *reinterpret_cast<const bf16x8*>(&Pt[wv * 2 + ih][c * PAD + 32 + g * 8]);
            #pragma unroll
            for (int dt = 0; dt < 4; ++dt) {
                o[dt][ih] = __builtin_amdgcn_mfma_f32_16x16x32_bf16(aq[dt][0], p0, o[dt][ih], 0, 0, 0);
                o[dt][ih] = __builtin_amdgcn_mfma_f32_16x16x32_bf16(aq[dt][1], p1, o[dt][ih], 0, 0, 0);
            }
        }
        bar_lds();
    }

    // epilogue: lane holds outT[dt*16+g*4+r][ibase+ih*16+c] -> f32x4 stores
    float* outb = (z ? out1 : out0) + (size_t)b * TN * DN;
    #pragma unroll
    for (int dt = 0; dt < 4; ++dt) {
        #pragma unroll
        for (int ih = 0; ih < 2; ++ih) {
            float4 v4;
            v4.x = o[dt][ih][0]; v4.y = o[dt][ih][1];
            v4.z = o[dt][ih][2]; v4.w = o[dt][ih][3];
            *reinterpret_cast<float4*>(
                &outb[(size_t)(ibase + ih * 16 + c) * DN + dt * 16 + g * 4]) = v4;
        }
    }
}

// ---------------------------------------------------------------------------
// Kernel R: out += part1 (exactly 1 float4 per thread).
// ---------------------------------------------------------------------------
__global__ __launch_bounds__(256) void reduce_kernel(
    float* __restrict__ out, const float* __restrict__ part1)
{
    const size_t i = (size_t)blockIdx.x * 256 + threadIdx.x;
    float4 a = reinterpret_cast<float4*>(out)[i];
    float4 b = reinterpret_cast<const float4*>(part1)[i];
    a.x += b.x; a.y += b.y; a.z += b.z; a.w += b.w;
    reinterpret_cast<float4*>(out)[i] = a;
}

extern "C" void kernel_launch(void* const* d_in, const int* in_sizes, int n_in,
                              void* d_out, int out_size, void* d_ws, size_t ws_size,
                              hipStream_t stream) {
    const float* x  = (const float*)d_in[0];
    const float* Wq = (const float*)d_in[1];
    const float* bq = (const float*)d_in[2];
    float* out = (float*)d_out;

    short* Qb   = (short*)d_ws;                           // 4 MB
    short* QTb  = Qb + (size_t)BN * TN * DN;              // 4 MB
    short* RT   = QTb + (size_t)BN * TN * DN;             // 4 MB
    float* lpar = (float*)(RT + (size_t)BN * TN * DN);    // 512 KB
    short* WTh  = (short*)(lpar + (size_t)4 * BN * TN);   // 64 KB
    short* WTl  = WTh + (size_t)DN * EN;                  // 64 KB
    float* part1 = (float*)(WTl + (size_t)DN * EN);       // 8 MB

    wprep_kernel<<<dim3(EN / 64), dim3(256), 0, stream>>>(Wq, WTh, WTl);
    qproj_kernel<<<dim3(BN * TN / 64), dim3(256), 0, stream>>>(x, WTh, WTl, bq, Qb, QTb);
    stats_kernel<<<dim3(TN / 64, BN, 4), dim3(256), 0, stream>>>(Qb, lpar);
    fuse_kernel<<<dim3(BN * DN * TN / 8 / 256), dim3(256), 0, stream>>>(QTb, lpar, RT);
    pv_kernel<<<dim3(TN / 128, BN, 2), dim3(256), 0, stream>>>(Qb, RT, out, part1);
    reduce_kernel<<<dim3(BN * TN * DN / 4 / 256), dim3(256), 0, stream>>>(out, part1);
}